// Round 9
// baseline (599.173 us; speedup 1.0000x reference)
//
#include <hip/hip_runtime.h>
#include <math.h>

#define NG 360
#define NV 100
#define ND 32
#define NU 512
#define NT 15
#define NVOC 5000
#define NH 8
#define NE 544
#define NHD 68
#define OFF_SCORES 4800000
#define INV_SQRT_HD 0.12126781f
#define CS_SCALE 43.65636f

typedef short bf16x8 __attribute__((ext_vector_type(8)));
typedef float f32x4 __attribute__((ext_vector_type(4)));
typedef unsigned short u16x4 __attribute__((ext_vector_type(4)));

__device__ __forceinline__ float leaky(float x) { return x >= 0.f ? x : 0.2f * x; }
__device__ __forceinline__ float sigm(float x) { return 1.f / (1.f + expf(-x)); }
__device__ __forceinline__ unsigned short f2bf(float x) {
    unsigned b = __float_as_uint(x);
    return (unsigned short)((b + 0x7FFFu + ((b >> 16) & 1u)) >> 16);
}

// ---------- Fused pre-pass 1: all input-only work ----------
// blocks [0,563): transpose features -> fX
// [563,819): kWm (Wm fold -> WA2 rows 0..255, bm, Wmf)
// [819,947): kInit (abf, cT)
// [947,962): kEmbed
// [962,14930): kPrep (weight converts)
__global__ __launch_bounds__(256) void kPre1(
        const float* __restrict__ features, const float* __restrict__ in_w,
        const float* __restrict__ in_b, const float* __restrict__ a0,
        const float* __restrict__ c0, const int* __restrict__ text,
        const float* __restrict__ emb, const float* __restrict__ Whh,
        const float* __restrict__ W1, const float* __restrict__ Wih,
        const float* __restrict__ W2,
        float* __restrict__ fX, unsigned short* __restrict__ WA2,
        float* __restrict__ bm, float* __restrict__ Wmf,
        unsigned short* __restrict__ abf, float* __restrict__ cT,
        unsigned short* __restrict__ xbf, unsigned short* __restrict__ W1x,
        unsigned short* __restrict__ Wihx, unsigned short* __restrict__ W2bf,
        float* __restrict__ Wc) {
    __shared__ float smem[64 * 65];
    int bid = (int)blockIdx.x, tid = (int)threadIdx.x;

    if (bid < 563) {
        // transpose features -> fX[col][b]
        int c0_ = bid * 64;
        int c = tid & 63, q0 = tid >> 6;
        for (int i = 0; i < 16; ++i) {
            int b = q0 + (i << 2);
            int col = c0_ + c;
            float v = (col < NG * NV) ? features[b * (NG * NV) + col] : 0.f;
            smem[c * 65 + b] = v;
        }
        __syncthreads();
        int b2 = tid & 63, cr = tid >> 6;
        for (int i = 0; i < 16; ++i) {
            int c2 = cr + (i << 2);
            int col = c0_ + c2;
            if (col < NG * NV) fX[col * 64 + b2] = smem[c2 * 65 + b2];
        }
        return;
    }
    if (bid < 819) {
        // kWm: r = bid-563
        float* wk = smem;  // [68]
        int r = bid - 563;
        int h = r >> 5, c = r & 31;
        if (tid < 68) wk[tid] = in_w[(size_t)(NE + h * NHD + tid) * NE + c];
        __syncthreads();
        float a0_ = 0.f, a1 = 0.f;
        for (int d = 0; d < NHD; ++d) {
            const float* wq = in_w + (size_t)(h * NHD + d) * NE + 32;
            float wkd = wk[d];
            a0_ = fmaf(wkd, wq[tid], a0_);
            a1 = fmaf(wkd, wq[tid + 256], a1);
        }
        WA2[(size_t)r * 512 + tid] = f2bf(a0_);
        WA2[(size_t)r * 512 + tid + 256] = f2bf(a1);
        // Wmf[r][d] = sum_e wk[e] * Wq[e][d] (feature cols 0..31), fp32
        if (tid < 32) {
            float a = 0.f;
            for (int e = 0; e < NHD; ++e)
                a = fmaf(wk[e], in_w[(size_t)(h * NHD + e) * NE + tid], a);
            Wmf[r * 32 + tid] = a;
        }
        __syncthreads();
        if (tid < 68) wk[tid] = wk[tid] * in_b[h * NHD + tid];
        __syncthreads();
        if (tid == 0) {
            float s = 0.f;
            for (int d = 0; d < NHD; ++d) s += wk[d];
            bm[r] = s;
        }
        return;
    }
    if (bid < 947) {
        int idx = (bid - 819) * 256 + tid;
        abf[idx] = f2bf(a0[idx]);
        cT[idx] = c0[idx];
        return;
    }
    if (bid < 962) {
        int t = bid - 947;
        int b = tid >> 2, seg = (tid & 3) * 128;
        int row = text[b * NT + t];
        const float* er = emb + (size_t)row * NU;
        unsigned short* dst = xbf + ((size_t)t * 64 + b) * 512;
        for (int i = 0; i < 128; ++i) dst[seg + i] = f2bf(er[seg + i]);
        return;
    }
    {
        int idx = (bid - 962) * 256 + tid;
        if (idx < 1048576) {                       // Whh [2048][512]
            WA2[256 * 512 + idx] = f2bf(Whh[idx]);
        } else if ((idx -= 1048576) < 131072) {    // W1 [256][512]
            W1x[idx] = f2bf(W1[idx]);
        } else if ((idx -= 131072) < 1048576) {    // Wih cols 32.. -> Wihx
            int r = idx >> 9, k = idx & 511;
            Wihx[idx] = f2bf(Wih[(size_t)r * NE + 32 + k]);
        } else if ((idx -= 1048576) < 1282048) {   // W2 + 8 pad rows
            W2bf[idx] = (idx < 1280000) ? f2bf(W2[idx]) : (unsigned short)0;
        } else {                                   // Wc [2048][32]
            idx -= 1282048;
            int r = idx >> 5, d = idx & 31;
            Wc[idx] = Wih[(size_t)r * NE + d];
        }
        return;
    }
}

// ---------- Encoder: 360 blocks, enc_W panel staged in LDS ----------
__global__ __launch_bounds__(256) void kEnc(
        const float* __restrict__ fX, const float* __restrict__ enc_W,
        const float* __restrict__ enc_b, const float* __restrict__ enc_g,
        const float* __restrict__ enc_beta, float* __restrict__ featB) {
    __shared__ float fxs[6400];
    __shared__ float wbs[3200];
    __shared__ float ps[256], pq[256];
    int g = (int)blockIdx.x, tid = (int)threadIdx.x;
    #pragma unroll
    for (int k = 0; k < 25; ++k) fxs[tid + k * 256] = fX[g * 6400 + tid + k * 256];
    for (int k = tid; k < 3200; k += 256) wbs[k] = enc_W[(size_t)g * 3200 + k];
    __syncthreads();
    int lane = tid & 63, w = tid >> 6, d0 = w * 8;
    float acc[8];
    #pragma unroll
    for (int j = 0; j < 8; ++j) acc[j] = enc_b[g * 32 + d0 + j];
    const float* wb = wbs + d0 * 100;
    #pragma unroll 4
    for (int v = 0; v < 100; ++v) {
        float fv = fxs[v * 64 + lane];
        #pragma unroll
        for (int j = 0; j < 8; ++j) acc[j] += fv * wb[j * 100 + v];
    }
    float sm = 0.f, sq = 0.f;
    #pragma unroll
    for (int j = 0; j < 8; ++j) { sm += acc[j]; sq += acc[j] * acc[j]; }
    ps[tid] = sm; pq[tid] = sq;
    __syncthreads();
    float m = (ps[lane] + ps[64 + lane] + ps[128 + lane] + ps[192 + lane]) * (1.f / 32.f);
    float q = (pq[lane] + pq[64 + lane] + pq[128 + lane] + pq[192 + lane]);
    float var = q * (1.f / 32.f) - m * m;
    float rstd = 1.f / sqrtf(var + 1e-5f);
    #pragma unroll
    for (int j = 0; j < 8; ++j) {
        int d = d0 + j;
        float x = (acc[j] - m) * rstd * enc_g[d] + enc_beta[d];
        featB[((size_t)lane * NG + g) * 32 + d] = leaky(x);
    }
}

// ---------- gihx MFMA: 1920 blocks (math identical to R8's fused branch) ----------
__global__ __launch_bounds__(256) void kGihx(
        const unsigned short* __restrict__ Wihx, const unsigned short* __restrict__ xbf,
        const float* __restrict__ bih, const float* __restrict__ bhh,
        float* __restrict__ gihxAll) {
    int wid = __builtin_amdgcn_readfirstlane((int)blockIdx.x * 4 + ((int)threadIdx.x >> 6));
    int lane = (int)threadIdx.x & 63;
    int mt = wid / 60, nt = wid % 60;
    int m0 = mt * 16, col = lane & 15, q = lane >> 4;
    const unsigned short* aB = Wihx + (size_t)(m0 + col) * 512 + q * 8;
    const unsigned short* bB = xbf + (size_t)(nt * 16 + col) * 512 + q * 8;
    f32x4 acc = {0.f, 0.f, 0.f, 0.f};
    #pragma unroll
    for (int kk = 0; kk < 16; ++kk) {
        bf16x8 af = *(const bf16x8*)(aB + kk * 32);
        bf16x8 bf = *(const bf16x8*)(bB + kk * 32);
        acc = __builtin_amdgcn_mfma_f32_16x16x32_bf16(af, bf, acc, 0, 0, 0);
    }
    int gcol = nt * 16 + col, t = gcol >> 6, b = gcol & 63;
    int n0 = m0 + q * 4;
    float4 o;
    o.x = acc[0] + bih[n0] + bhh[n0];
    o.y = acc[1] + bih[n0 + 1] + bhh[n0 + 1];
    o.z = acc[2] + bih[n0 + 2] + bhh[n0 + 2];
    o.w = acc[3] + bih[n0 + 3] + bhh[n0 + 3];
    *(float4*)(gihxAll + ((size_t)(t * 64 + b)) * 2048 + n0) = o;
}

// ---------- Fused pre-pass 3: fmean_b + mq_b + cSb, 64 blocks (one per b) ----------
__global__ __launch_bounds__(256) void kCS2(const float* __restrict__ featB,
                                            const float* __restrict__ Wmf,
                                            float* __restrict__ cSb) {
    __shared__ float red[256];
    __shared__ float fmeanL[32];
    __shared__ float mqL[256];
    int b = (int)blockIdx.x, tid = (int)threadIdx.x;
    int s = tid >> 5, d = tid & 31;
    float acc = 0.f;
    for (int g = s; g < NG; g += 8) acc += featB[((size_t)b * NG + g) * 32 + d];
    red[tid] = acc;
    __syncthreads();
    if (tid < 32) {
        float f = 0.f;
        #pragma unroll
        for (int ss = 0; ss < 8; ++ss) f += red[ss * 32 + tid];
        fmeanL[tid] = f * (1.f / 360.f);
    }
    __syncthreads();
    {
        const float* wr = Wmf + tid * 32;
        float a = 0.f;
        #pragma unroll
        for (int dd = 0; dd < 32; dd += 4) {
            float4 f4 = *(const float4*)(wr + dd);
            a = fmaf(f4.x, fmeanL[dd], a);
            a = fmaf(f4.y, fmeanL[dd + 1], a);
            a = fmaf(f4.z, fmeanL[dd + 2], a);
            a = fmaf(f4.w, fmeanL[dd + 3], a);
        }
        mqL[tid] = a;
    }
    __syncthreads();
    for (int j = tid; j < NG; j += 256) {
        const float* fb = featB + ((size_t)b * NG + j) * 32;
        float v[8] = {0.f, 0.f, 0.f, 0.f, 0.f, 0.f, 0.f, 0.f};
        #pragma unroll
        for (int dc = 0; dc < 32; dc += 4) {
            float4 f = *(const float4*)(fb + dc);
            #pragma unroll
            for (int h = 0; h < 8; ++h) {
                v[h] = fmaf(f.x, mqL[h * 32 + dc], v[h]);
                v[h] = fmaf(f.y, mqL[h * 32 + dc + 1], v[h]);
                v[h] = fmaf(f.z, mqL[h * 32 + dc + 2], v[h]);
                v[h] = fmaf(f.w, mqL[h * 32 + dc + 3], v[h]);
            }
        }
        #pragma unroll
        for (int h = 0; h < 8; ++h)
            cSb[(size_t)b * 2880 + h * NG + j] = v[h] * CS_SCALE;
    }
}

// ---------- Per-step ----------

// MFMA: [m(256); ghh(2048)] = WA2[2304][512] · abf[64][512]^T. 144 blocks.
__global__ __launch_bounds__(256) void kAMF2(
        const unsigned short* __restrict__ WA2, const float* __restrict__ bm,
        const unsigned short* __restrict__ abf,
        float* __restrict__ mAll, float* __restrict__ ghhT) {
    int wid = __builtin_amdgcn_readfirstlane((int)blockIdx.x * 4 + ((int)threadIdx.x >> 6));
    int lane = (int)threadIdx.x & 63;
    int mt = wid >> 2, bt = wid & 3;
    int m0 = mt * 16, col = lane & 15, q = lane >> 4;
    const unsigned short* aB = WA2 + (size_t)(m0 + col) * NU + q * 8;
    const unsigned short* bB = abf + (size_t)(bt * 16 + col) * NU + q * 8;
    f32x4 acc = {0.f, 0.f, 0.f, 0.f};
    #pragma unroll
    for (int kk = 0; kk < 16; ++kk) {
        bf16x8 af = *(const bf16x8*)(aB + kk * 32);
        bf16x8 bf = *(const bf16x8*)(bB + kk * 32);
        acc = __builtin_amdgcn_mfma_f32_16x16x32_bf16(af, bf, acc, 0, 0, 0);
    }
    int b = bt * 16 + col;
    if (m0 < 256) {
        #pragma unroll
        for (int r = 0; r < 4; ++r) {
            int row = m0 + q * 4 + r;
            mAll[b * 256 + row] = acc[r] + bm[row];
        }
    } else {
        int n0 = m0 - 256 + q * 4;
        float4 o; o.x = acc[0]; o.y = acc[1]; o.z = acc[2]; o.w = acc[3];
        *(float4*)(ghhT + (size_t)b * 2048 + n0) = o;
    }
}

// Fused step: attention + LSTM + LN + emit abf/sbf. 64 blocks, one per b.
__global__ __launch_bounds__(256) void kStep(
        const float* __restrict__ mAll,
        const float* __restrict__ featB, const float* __restrict__ cSb,
        const float* __restrict__ gihxT, const float* __restrict__ ghhT,
        const float* __restrict__ Wc,
        const float* __restrict__ ln_g, const float* __restrict__ ln_b,
        float* __restrict__ cT,
        unsigned short* __restrict__ abf, unsigned short* __restrict__ sbf,
        float* __restrict__ out, int t) {
    __shared__ float mL[256];
    __shared__ float eL[8 * 384];
    __shared__ float cL[8 * 384];
    __shared__ float WL[360];
    __shared__ float redS[4][8], redC[4][8];
    __shared__ float SevL[8], CevL[8];
    __shared__ float cpart[256];
    __shared__ float ctxL[32];
    int b = (int)blockIdx.x, tid = (int)threadIdx.x;
    int lane = tid & 63, w = tid >> 6;

    mL[tid] = mAll[b * 256 + tid];
    __syncthreads();

    float eS[8] = {0.f, 0.f, 0.f, 0.f, 0.f, 0.f, 0.f, 0.f};
    float eC[8] = {0.f, 0.f, 0.f, 0.f, 0.f, 0.f, 0.f, 0.f};
    for (int j = tid; j < NG; j += 256) {
        const float* fb = featB + ((size_t)b * NG + j) * 32;
        float v[8] = {0.f, 0.f, 0.f, 0.f, 0.f, 0.f, 0.f, 0.f};
        #pragma unroll
        for (int dc = 0; dc < 32; dc += 4) {
            float4 f = *(const float4*)(fb + dc);
            #pragma unroll
            for (int h = 0; h < 8; ++h) {
                v[h] = fmaf(f.x, mL[h * 32 + dc], v[h]);
                v[h] = fmaf(f.y, mL[h * 32 + dc + 1], v[h]);
                v[h] = fmaf(f.z, mL[h * 32 + dc + 2], v[h]);
                v[h] = fmaf(f.w, mL[h * 32 + dc + 3], v[h]);
            }
        }
        #pragma unroll
        for (int h = 0; h < 8; ++h) {
            float e = expf(v[h] * INV_SQRT_HD);
            float c = cSb[(size_t)b * 2880 + h * NG + j];
            eL[h * 384 + j] = e;
            cL[h * 384 + j] = c;
            eS[h] += e;
            eC[h] += c * e;
        }
    }
    #pragma unroll
    for (int h = 0; h < 8; ++h) {
        #pragma unroll
        for (int off = 32; off > 0; off >>= 1) {
            eS[h] += __shfl_xor(eS[h], off);
            eC[h] += __shfl_xor(eC[h], off);
        }
    }
    if (lane == 0) {
        #pragma unroll
        for (int h = 0; h < 8; ++h) { redS[w][h] = eS[h]; redC[w][h] = eC[h]; }
    }
    __syncthreads();
    if (tid < 8) {
        float s = 0.f, c = 0.f;
        #pragma unroll
        for (int ww = 0; ww < 4; ++ww) { s += redS[ww][tid]; c += redC[ww][tid]; }
        SevL[tid] = s; CevL[tid] = c;
    }
    __syncthreads();
    float invS[8], cevM[8];
    #pragma unroll
    for (int h = 0; h < 8; ++h) {
        float iv = 1.f / SevL[h];
        invS[h] = iv;
        cevM[h] = CevL[h] * iv;
    }
    for (int j = tid; j < NG; j += 256) {
        float acc = 0.f;
        #pragma unroll
        for (int h = 0; h < 8; ++h) {
            float e = eL[h * 384 + j];
            float c = cL[h * 384 + j];
            acc += e * invS[h] * (1.f + (c - cevM[h]) * (1.f / 360.f));
        }
        float W = acc * 0.125f;
        WL[j] = W;
        out[OFF_SCORES + (size_t)b * (NT * NG) + t * NG + j] = W;
    }
    __syncthreads();
    {
        int d = tid & 31, sl = tid >> 5;
        float a = 0.f;
        for (int i = 0; i < 45; ++i) {
            int j = sl * 45 + i;
            a += WL[j] * featB[((size_t)b * NG + j) * 32 + d];
        }
        cpart[tid] = a;
    }
    __syncthreads();
    if (tid < 32) {
        float s = 0.f;
        #pragma unroll
        for (int ss = 0; ss < 8; ++ss) s += cpart[ss * 32 + tid];
        ctxL[tid] = s;
    }
    __syncthreads();

    const float* gihxB = gihxT + (size_t)b * 2048;
    const float* ghhB  = ghhT + (size_t)b * 2048;
    float* cB = cT + (size_t)b * 512;
    float hv[2];
    float ssum = 0.f, qsum = 0.f;
    #pragma unroll
    for (int ii = 0; ii < 2; ++ii) {
        int u = tid + ii * 256;
        float g4[4];
        #pragma unroll
        for (int q = 0; q < 4; ++q) {
            int n = q * 512 + u;
            float gv = gihxB[n] + ghhB[n];
            const float* wr = Wc + (size_t)n * 32;
            #pragma unroll
            for (int d = 0; d < 32; d += 4) {
                float4 f = *(const float4*)(wr + d);
                gv = fmaf(ctxL[d], f.x, gv);
                gv = fmaf(ctxL[d + 1], f.y, gv);
                gv = fmaf(ctxL[d + 2], f.z, gv);
                gv = fmaf(ctxL[d + 3], f.w, gv);
            }
            g4[q] = gv;
        }
        float ig = sigm(g4[0]), fg = sigm(g4[1]), gg = tanhf(g4[2]), og = sigm(g4[3]);
        float cn = fg * cB[u] + ig * gg;
        cB[u] = cn;
        hv[ii] = og * tanhf(cn);
        ssum += hv[ii]; qsum += hv[ii] * hv[ii];
    }
    #pragma unroll
    for (int off = 32; off > 0; off >>= 1) {
        ssum += __shfl_xor(ssum, off);
        qsum += __shfl_xor(qsum, off);
    }
    if (lane == 0) { cpart[w] = ssum; cpart[8 + w] = qsum; }
    __syncthreads();
    float ms = cpart[0] + cpart[1] + cpart[2] + cpart[3];
    float qs = cpart[8] + cpart[9] + cpart[10] + cpart[11];
    float m = ms * (1.f / 512.f);
    float var = qs * (1.f / 512.f) - m * m;
    float rstd = 1.f / sqrtf(var + 1e-5f);
    float mneg = -m * rstd;
    unsigned short* srow = sbf + ((size_t)t * 64 + b) * 512;
    #pragma unroll
    for (int ii = 0; ii < 2; ++ii) {
        int u = tid + ii * 256;
        float aval = fmaf(fmaf(hv[ii], rstd, mneg), ln_g[u], ln_b[u]);
        abf[(size_t)b * 512 + u] = f2bf(aval);
        srow[u] = f2bf(leaky(aval));
    }
}

// ---------- Post-loop head ----------

__global__ __launch_bounds__(256) void kHeadMF(
        const unsigned short* __restrict__ W1x, const unsigned short* __restrict__ sbf,
        const float* __restrict__ b1, unsigned short* __restrict__ h1bf) {
    int wid = __builtin_amdgcn_readfirstlane((int)blockIdx.x * 4 + ((int)threadIdx.x >> 6));
    int lane = (int)threadIdx.x & 63;
    int mt = wid / 60, nt = wid % 60;
    int m0 = mt * 16, col = lane & 15, q = lane >> 4;
    const unsigned short* aB = W1x + (size_t)(m0 + col) * NU + q * 8;
    const unsigned short* bB = sbf + (size_t)(nt * 16 + col) * NU + q * 8;
    f32x4 acc = {0.f, 0.f, 0.f, 0.f};
    #pragma unroll
    for (int kk = 0; kk < 16; ++kk) {
        bf16x8 af = *(const bf16x8*)(aB + kk * 32);
        bf16x8 bf = *(const bf16x8*)(bB + kk * 32);
        acc = __builtin_amdgcn_mfma_f32_16x16x32_bf16(af, bf, acc, 0, 0, 0);
    }
    int gcol = nt * 16 + col;
    u16x4 pk;
    #pragma unroll
    for (int r = 0; r < 4; ++r) {
        float v = leaky(acc[r] + b1[m0 + q * 4 + r]);
        pk[r] = f2bf(v);
    }
    *(u16x4*)(h1bf + (size_t)gcol * 256 + m0 + q * 4) = pk;
}

// MFMA logits: wave = (t, mt); loops 4 ntiles reusing A fragments. 1174 blocks.
__global__ __launch_bounds__(256) void kLogitsMF(const unsigned short* __restrict__ W2bf,
                                                 const unsigned short* __restrict__ h1bfT,
                                                 const float* __restrict__ b2,
                                                 float* __restrict__ lgAll, float* __restrict__ zPm) {
    int wid = __builtin_amdgcn_readfirstlane((int)blockIdx.x * 4 + ((int)threadIdx.x >> 6));
    if (wid >= NT * 313) return;
    int lane = (int)threadIdx.x & 63;
    int t = wid / 313;
    int mt = wid - t * 313;
    int m0 = mt * 16;
    int q = lane >> 4, col = lane & 15;
    const unsigned short* aBase = W2bf + (size_t)(m0 + col) * 256 + q * 8;
    bf16x8 af[8];
    #pragma unroll
    for (int kk = 0; kk < 8; ++kk) af[kk] = *(const bf16x8*)(aBase + kk * 32);

    float b2r[4];
    #pragma unroll
    for (int r = 0; r < 4; ++r) {
        int row = m0 + q * 4 + r;
        b2r[r] = (row < NVOC) ? b2[row] : 0.f;
    }

    #pragma unroll
    for (int nt = 0; nt < 4; ++nt) {
        const unsigned short* bBase = h1bfT + ((size_t)t * 64 + nt * 16 + col) * 256 + q * 8;
        f32x4 acc = {0.f, 0.f, 0.f, 0.f};
        #pragma unroll
        for (int kk = 0; kk < 8; ++kk) {
            bf16x8 bf = *(const bf16x8*)(bBase + kk * 32);
            acc = __builtin_amdgcn_mfma_f32_16x16x32_bf16(af[kk], bf, acc, 0, 0, 0);
        }
        float eS = 0.f;
        #pragma unroll
        for (int r = 0; r < 4; ++r) {
            int row = m0 + q * 4 + r;
            if (row < NVOC) {
                float e = expf(acc[r] + b2r[r]);
                lgAll[((size_t)t * NVOC + row) * 64 + nt * 16 + col] = e;
                eS += e;
            }
        }
        eS += __shfl_xor(eS, 16);
        eS += __shfl_xor(eS, 32);
        if (lane < 16)
            zPm[((size_t)t * 313 + mt) * 64 + nt * 16 + col] = eS;
    }
}

__global__ __launch_bounds__(256) void kZinv(const float* __restrict__ zPm, float* __restrict__ zInv) {
    __shared__ float red[256];
    int t = (int)blockIdx.x, tid = (int)threadIdx.x;
    int lane = tid & 63, w = tid >> 6;
    float p = 0.f;
    for (int i = w; i < 313; i += 4) p += zPm[((size_t)t * 313 + i) * 64 + lane];
    red[tid] = p;
    __syncthreads();
    if (tid < 64) {
        float z = red[tid] + red[64 + tid] + red[128 + tid] + red[192 + tid];
        zInv[t * 64 + tid] = 1.f / z;
    }
}

__global__ __launch_bounds__(256) void kOut(const float* __restrict__ lgAll,
                                            const float* __restrict__ zInv, float* __restrict__ out) {
    __shared__ float tile[64 * 65];
    int bid = (int)blockIdx.x;
    int t = bid / 79, nt = bid % 79;
    int n0 = nt * 64;
    int tid = (int)threadIdx.x, lane = tid & 63, w = tid >> 6;
    const float* lg = lgAll + (size_t)t * (NVOC * 64);
    float invZ = zInv[t * 64 + lane];
    for (int i = 0; i < 16; ++i) {
        int r = w * 16 + i, n = n0 + r;
        if (n < NVOC) tile[r * 65 + lane] = lg[n * 64 + lane] * invZ;
    }
    __syncthreads();
    for (int i = 0; i < 16; ++i) {
        int b = w * 16 + i;
        int n = n0 + lane;
        if (n < NVOC) out[(size_t)b * (NT * NVOC) + t * NVOC + n] = tile[lane * 65 + b];
    }
}

// ---------- Launch ----------
extern "C" void kernel_launch(void* const* d_in, const int* in_sizes, int n_in,
                              void* d_out, int out_size, void* d_ws, size_t ws_size,
                              hipStream_t stream) {
    const float* features = (const float*)d_in[0];
    const int*   text     = (const int*)d_in[1];
    const float* a0       = (const float*)d_in[2];
    const float* c0       = (const float*)d_in[3];
    const float* enc_W    = (const float*)d_in[4];
    const float* enc_b    = (const float*)d_in[5];
    const float* enc_g    = (const float*)d_in[6];
    const float* enc_beta = (const float*)d_in[7];
    const float* emb      = (const float*)d_in[8];
    const float* in_w     = (const float*)d_in[9];
    const float* in_b     = (const float*)d_in[10];
    const float* Wih      = (const float*)d_in[11];
    const float* Whh      = (const float*)d_in[12];
    const float* bih      = (const float*)d_in[13];
    const float* bhh      = (const float*)d_in[14];
    const float* ln_g     = (const float*)d_in[15];
    const float* ln_b     = (const float*)d_in[16];
    const float* W1       = (const float*)d_in[17];
    const float* b1       = (const float*)d_in[18];
    const float* W2       = (const float*)d_in[19];
    const float* b2       = (const float*)d_in[20];
    float* out = (float*)d_out;

    float* ws = (float*)d_ws;
    size_t off = 0;
    auto alloc = [&](size_t n) { float* p = ws + off; off += (n + 63) & ~(size_t)63; return p; };
    float* lgAll   = alloc((size_t)NT * NVOC * 64);   // aliased as fX pre-loop
    float* fX      = lgAll;
    float* featB   = alloc((size_t)64 * NG * ND);
    float* gihxAll = alloc((size_t)NT * 64 * 2048);
    float* mAll    = alloc((size_t)64 * 256);
    float* cSb     = alloc((size_t)64 * NH * NG);
    float* cT_     = alloc((size_t)64 * NU);
    float* ghhT    = alloc((size_t)64 * 2048);
    float* Wc      = alloc((size_t)2048 * 32);
    float* bm      = alloc((size_t)256);
    float* Wmf     = alloc((size_t)256 * 32);
    float* zPm     = alloc((size_t)NT * 313 * 64);
    float* zInv    = alloc((size_t)NT * 64);
    unsigned short* WA2  = (unsigned short*)alloc((size_t)2304 * 256);  // [2304][512] bf16
    unsigned short* W1x  = (unsigned short*)alloc((size_t)256 * 256);
    unsigned short* abf  = (unsigned short*)alloc((size_t)64 * 256);
    unsigned short* sbf  = (unsigned short*)alloc((size_t)960 * 256);
    unsigned short* Wihx = (unsigned short*)alloc((size_t)2048 * 256);
    unsigned short* xbf  = (unsigned short*)alloc((size_t)960 * 256);
    unsigned short* W2bf = (unsigned short*)alloc((size_t)5008 * 128);
    unsigned short* h1bf = (unsigned short*)alloc((size_t)NT * 64 * 128);

    // fused pre-passes
    kPre1<<<14930, 256, 0, stream>>>(features, in_w, in_b, a0, c0, text, emb,
                                     Whh, W1, Wih, W2,
                                     fX, WA2, bm, Wmf, abf, cT_, xbf, W1x,
                                     Wihx, W2bf, Wc);
    kEnc<<<NG, 256, 0, stream>>>(fX, enc_W, enc_b, enc_g, enc_beta, featB);
    kGihx<<<1920, 256, 0, stream>>>(Wihx, xbf, bih, bhh, gihxAll);
    kCS2<<<64, 256, 0, stream>>>(featB, Wmf, cSb);

    for (int t = 0; t < NT; ++t) {
        kAMF2<<<144, 256, 0, stream>>>(WA2, bm, abf, mAll, ghhT);
        kStep<<<64, 256, 0, stream>>>(mAll, featB, cSb,
                                      gihxAll + (size_t)t * 64 * 2048, ghhT, Wc,
                                      ln_g, ln_b, cT_, abf, sbf, out, t);
    }

    kHeadMF<<<240, 256, 0, stream>>>(W1x, sbf, b1, h1bf);
    kLogitsMF<<<1174, 256, 0, stream>>>(W2bf, h1bf, b2, lgAll, zPm);
    kZinv<<<NT, 256, 0, stream>>>(zPm, zInv);
    kOut<<<NT * 79, 256, 0, stream>>>(lgAll, zInv, out);
}

// Round 10
// 589.050 us; speedup vs baseline: 1.0172x; 1.0172x over previous
//
#include <hip/hip_runtime.h>
#include <math.h>

#define NG 360
#define NV 100
#define ND 32
#define NU 512
#define NT 15
#define NVOC 5000
#define NH 8
#define NE 544
#define NHD 68
#define OFF_SCORES 4800000
#define INV_SQRT_HD 0.12126781f
#define CS_SCALE 43.65636f

typedef short bf16x8 __attribute__((ext_vector_type(8)));
typedef float f32x4 __attribute__((ext_vector_type(4)));
typedef unsigned short u16x4 __attribute__((ext_vector_type(4)));

__device__ __forceinline__ float leaky(float x) { return x >= 0.f ? x : 0.2f * x; }
__device__ __forceinline__ float sigm(float x) { return 1.f / (1.f + expf(-x)); }
__device__ __forceinline__ unsigned short f2bf(float x) {
    unsigned b = __float_as_uint(x);
    return (unsigned short)((b + 0x7FFFu + ((b >> 16) & 1u)) >> 16);
}

// ---------- Fused pre-pass 1: all input-only work ----------
// blocks [0,563): transpose features -> fX
// [563,819): kWm (Wm fold -> WA2 rows 0..255, bm, Wmf)
// [819,947): kInit (abf, cT)
// [947,962): kEmbed
// [962,14930): kPrep (weight converts)
__global__ __launch_bounds__(256) void kPre1(
        const float* __restrict__ features, const float* __restrict__ in_w,
        const float* __restrict__ in_b, const float* __restrict__ a0,
        const float* __restrict__ c0, const int* __restrict__ text,
        const float* __restrict__ emb, const float* __restrict__ Whh,
        const float* __restrict__ W1, const float* __restrict__ Wih,
        const float* __restrict__ W2,
        float* __restrict__ fX, unsigned short* __restrict__ WA2,
        float* __restrict__ bm, float* __restrict__ Wmf,
        unsigned short* __restrict__ abf, float* __restrict__ cT,
        unsigned short* __restrict__ xbf, unsigned short* __restrict__ W1x,
        unsigned short* __restrict__ Wihx, unsigned short* __restrict__ W2bf,
        float* __restrict__ Wc) {
    __shared__ float smem[64 * 65];
    int bid = (int)blockIdx.x, tid = (int)threadIdx.x;

    if (bid < 563) {
        // transpose features -> fX[col][b]
        int c0_ = bid * 64;
        int c = tid & 63, q0 = tid >> 6;
        for (int i = 0; i < 16; ++i) {
            int b = q0 + (i << 2);
            int col = c0_ + c;
            float v = (col < NG * NV) ? features[b * (NG * NV) + col] : 0.f;
            smem[c * 65 + b] = v;
        }
        __syncthreads();
        int b2 = tid & 63, cr = tid >> 6;
        for (int i = 0; i < 16; ++i) {
            int c2 = cr + (i << 2);
            int col = c0_ + c2;
            if (col < NG * NV) fX[col * 64 + b2] = smem[c2 * 65 + b2];
        }
        return;
    }
    if (bid < 819) {
        // kWm: r = bid-563
        float* wk = smem;  // [68]
        int r = bid - 563;
        int h = r >> 5, c = r & 31;
        if (tid < 68) wk[tid] = in_w[(size_t)(NE + h * NHD + tid) * NE + c];
        __syncthreads();
        float a0_ = 0.f, a1 = 0.f;
        for (int d = 0; d < NHD; ++d) {
            const float* wq = in_w + (size_t)(h * NHD + d) * NE + 32;
            float wkd = wk[d];
            a0_ = fmaf(wkd, wq[tid], a0_);
            a1 = fmaf(wkd, wq[tid + 256], a1);
        }
        WA2[(size_t)r * 512 + tid] = f2bf(a0_);
        WA2[(size_t)r * 512 + tid + 256] = f2bf(a1);
        // Wmf[r][d] = sum_e wk[e] * Wq[e][d] (feature cols 0..31), fp32
        if (tid < 32) {
            float a = 0.f;
            for (int e = 0; e < NHD; ++e)
                a = fmaf(wk[e], in_w[(size_t)(h * NHD + e) * NE + tid], a);
            Wmf[r * 32 + tid] = a;
        }
        __syncthreads();
        if (tid < 68) wk[tid] = wk[tid] * in_b[h * NHD + tid];
        __syncthreads();
        if (tid == 0) {
            float s = 0.f;
            for (int d = 0; d < NHD; ++d) s += wk[d];
            bm[r] = s;
        }
        return;
    }
    if (bid < 947) {
        int idx = (bid - 819) * 256 + tid;
        abf[idx] = f2bf(a0[idx]);
        cT[idx] = c0[idx];
        return;
    }
    if (bid < 962) {
        int t = bid - 947;
        int b = tid >> 2, seg = (tid & 3) * 128;
        int row = text[b * NT + t];
        const float* er = emb + (size_t)row * NU;
        unsigned short* dst = xbf + ((size_t)t * 64 + b) * 512;
        for (int i = 0; i < 128; ++i) dst[seg + i] = f2bf(er[seg + i]);
        return;
    }
    {
        int idx = (bid - 962) * 256 + tid;
        if (idx < 1048576) {                       // Whh [2048][512]
            WA2[256 * 512 + idx] = f2bf(Whh[idx]);
        } else if ((idx -= 1048576) < 131072) {    // W1 [256][512]
            W1x[idx] = f2bf(W1[idx]);
        } else if ((idx -= 131072) < 1048576) {    // Wih cols 32.. -> Wihx
            int r = idx >> 9, k = idx & 511;
            Wihx[idx] = f2bf(Wih[(size_t)r * NE + 32 + k]);
        } else if ((idx -= 1048576) < 1282048) {   // W2 + 8 pad rows
            W2bf[idx] = (idx < 1280000) ? f2bf(W2[idx]) : (unsigned short)0;
        } else {                                   // Wc [2048][32]
            idx -= 1282048;
            int r = idx >> 5, d = idx & 31;
            Wc[idx] = Wih[(size_t)r * NE + d];
        }
        return;
    }
}

// ---------- Fused pre-pass 2: encoder (blocks 0..359, enc_W staged in LDS)
//            + gihx MFMA (blocks 360..2279) — overlapped in one launch ----------
__global__ __launch_bounds__(256) void kEncGihx(
        const float* __restrict__ fX, const float* __restrict__ enc_W,
        const float* __restrict__ enc_b, const float* __restrict__ enc_g,
        const float* __restrict__ enc_beta, float* __restrict__ featB,
        const unsigned short* __restrict__ Wihx, const unsigned short* __restrict__ xbf,
        const float* __restrict__ bih, const float* __restrict__ bhh,
        float* __restrict__ gihxAll) {
    __shared__ float fxs[6400];
    __shared__ float wbs[3200];
    __shared__ float ps[256], pq[256];
    int bid = (int)blockIdx.x, tid = (int)threadIdx.x;
    if (bid < NG) {
        int g = bid;
        #pragma unroll
        for (int k = 0; k < 25; ++k) fxs[tid + k * 256] = fX[g * 6400 + tid + k * 256];
        for (int k = tid; k < 3200; k += 256) wbs[k] = enc_W[(size_t)g * 3200 + k];
        __syncthreads();
        int lane = tid & 63, w = tid >> 6, d0 = w * 8;
        float acc[8];
        #pragma unroll
        for (int j = 0; j < 8; ++j) acc[j] = enc_b[g * 32 + d0 + j];
        const float* wb = wbs + d0 * 100;
        #pragma unroll 4
        for (int v = 0; v < 100; ++v) {
            float fv = fxs[v * 64 + lane];
            #pragma unroll
            for (int j = 0; j < 8; ++j) acc[j] += fv * wb[j * 100 + v];
        }
        float sm = 0.f, sq = 0.f;
        #pragma unroll
        for (int j = 0; j < 8; ++j) { sm += acc[j]; sq += acc[j] * acc[j]; }
        ps[tid] = sm; pq[tid] = sq;
        __syncthreads();
        float m = (ps[lane] + ps[64 + lane] + ps[128 + lane] + ps[192 + lane]) * (1.f / 32.f);
        float q = (pq[lane] + pq[64 + lane] + pq[128 + lane] + pq[192 + lane]);
        float var = q * (1.f / 32.f) - m * m;
        float rstd = 1.f / sqrtf(var + 1e-5f);
        #pragma unroll
        for (int j = 0; j < 8; ++j) {
            int d = d0 + j;
            float x = (acc[j] - m) * rstd * enc_g[d] + enc_beta[d];
            featB[((size_t)lane * NG + g) * 32 + d] = leaky(x);
        }
        return;
    }
    // gihx MFMA
    int wid = __builtin_amdgcn_readfirstlane((bid - NG) * 4 + (tid >> 6));
    int lane = tid & 63;
    int mt = wid / 60, nt = wid % 60;
    int m0 = mt * 16, col = lane & 15, q = lane >> 4;
    const unsigned short* aB = Wihx + (size_t)(m0 + col) * 512 + q * 8;
    const unsigned short* bB = xbf + (size_t)(nt * 16 + col) * 512 + q * 8;
    f32x4 acc = {0.f, 0.f, 0.f, 0.f};
    #pragma unroll
    for (int kk = 0; kk < 16; ++kk) {
        bf16x8 af = *(const bf16x8*)(aB + kk * 32);
        bf16x8 bf = *(const bf16x8*)(bB + kk * 32);
        acc = __builtin_amdgcn_mfma_f32_16x16x32_bf16(af, bf, acc, 0, 0, 0);
    }
    int gcol = nt * 16 + col, t = gcol >> 6, b = gcol & 63;
    int n0 = m0 + q * 4;
    float4 o;
    o.x = acc[0] + bih[n0] + bhh[n0];
    o.y = acc[1] + bih[n0 + 1] + bhh[n0 + 1];
    o.z = acc[2] + bih[n0 + 2] + bhh[n0 + 2];
    o.w = acc[3] + bih[n0 + 3] + bhh[n0 + 3];
    *(float4*)(gihxAll + ((size_t)(t * 64 + b)) * 2048 + n0) = o;
}

// ---------- Fused pre-pass 3: fmean_b + mq_b + cSb, 64 blocks (one per b) ----------
__global__ __launch_bounds__(256) void kCS2(const float* __restrict__ featB,
                                            const float* __restrict__ Wmf,
                                            float* __restrict__ cSb) {
    __shared__ float red[256];
    __shared__ float fmeanL[32];
    __shared__ float mqL[256];
    int b = (int)blockIdx.x, tid = (int)threadIdx.x;
    int s = tid >> 5, d = tid & 31;
    float acc = 0.f;
    for (int g = s; g < NG; g += 8) acc += featB[((size_t)b * NG + g) * 32 + d];
    red[tid] = acc;
    __syncthreads();
    if (tid < 32) {
        float f = 0.f;
        #pragma unroll
        for (int ss = 0; ss < 8; ++ss) f += red[ss * 32 + tid];
        fmeanL[tid] = f * (1.f / 360.f);
    }
    __syncthreads();
    {
        const float* wr = Wmf + tid * 32;
        float a = 0.f;
        #pragma unroll
        for (int dd = 0; dd < 32; dd += 4) {
            float4 f4 = *(const float4*)(wr + dd);
            a = fmaf(f4.x, fmeanL[dd], a);
            a = fmaf(f4.y, fmeanL[dd + 1], a);
            a = fmaf(f4.z, fmeanL[dd + 2], a);
            a = fmaf(f4.w, fmeanL[dd + 3], a);
        }
        mqL[tid] = a;
    }
    __syncthreads();
    for (int j = tid; j < NG; j += 256) {
        const float* fb = featB + ((size_t)b * NG + j) * 32;
        float v[8] = {0.f, 0.f, 0.f, 0.f, 0.f, 0.f, 0.f, 0.f};
        #pragma unroll
        for (int dc = 0; dc < 32; dc += 4) {
            float4 f = *(const float4*)(fb + dc);
            #pragma unroll
            for (int h = 0; h < 8; ++h) {
                v[h] = fmaf(f.x, mqL[h * 32 + dc], v[h]);
                v[h] = fmaf(f.y, mqL[h * 32 + dc + 1], v[h]);
                v[h] = fmaf(f.z, mqL[h * 32 + dc + 2], v[h]);
                v[h] = fmaf(f.w, mqL[h * 32 + dc + 3], v[h]);
            }
        }
        #pragma unroll
        for (int h = 0; h < 8; ++h)
            cSb[(size_t)b * 2880 + h * NG + j] = v[h] * CS_SCALE;
    }
}

// ---------- Per-step ----------

// MFMA: [m(256); ghh(2048)] = WA2[2304][512] · abf[64][512]^T. 144 blocks.
__global__ __launch_bounds__(256) void kAMF2(
        const unsigned short* __restrict__ WA2, const float* __restrict__ bm,
        const unsigned short* __restrict__ abf,
        float* __restrict__ mAll, float* __restrict__ ghhT) {
    int wid = __builtin_amdgcn_readfirstlane((int)blockIdx.x * 4 + ((int)threadIdx.x >> 6));
    int lane = (int)threadIdx.x & 63;
    int mt = wid >> 2, bt = wid & 3;
    int m0 = mt * 16, col = lane & 15, q = lane >> 4;
    const unsigned short* aB = WA2 + (size_t)(m0 + col) * NU + q * 8;
    const unsigned short* bB = abf + (size_t)(bt * 16 + col) * NU + q * 8;
    f32x4 acc = {0.f, 0.f, 0.f, 0.f};
    #pragma unroll
    for (int kk = 0; kk < 16; ++kk) {
        bf16x8 af = *(const bf16x8*)(aB + kk * 32);
        bf16x8 bf = *(const bf16x8*)(bB + kk * 32);
        acc = __builtin_amdgcn_mfma_f32_16x16x32_bf16(af, bf, acc, 0, 0, 0);
    }
    int b = bt * 16 + col;
    if (m0 < 256) {
        #pragma unroll
        for (int r = 0; r < 4; ++r) {
            int row = m0 + q * 4 + r;
            mAll[b * 256 + row] = acc[r] + bm[row];
        }
    } else {
        int n0 = m0 - 256 + q * 4;
        float4 o; o.x = acc[0]; o.y = acc[1]; o.z = acc[2]; o.w = acc[3];
        *(float4*)(ghhT + (size_t)b * 2048 + n0) = o;
    }
}

// Fused step: attention + LSTM + LN + emit abf/sbf. 64 blocks, one per b.
__global__ __launch_bounds__(256) void kStep(
        const float* __restrict__ mAll,
        const float* __restrict__ featB, const float* __restrict__ cSb,
        const float* __restrict__ gihxT, const float* __restrict__ ghhT,
        const float* __restrict__ Wc,
        const float* __restrict__ ln_g, const float* __restrict__ ln_b,
        float* __restrict__ cT,
        unsigned short* __restrict__ abf, unsigned short* __restrict__ sbf,
        float* __restrict__ out, int t) {
    __shared__ float mL[256];
    __shared__ float eL[8 * 384];
    __shared__ float cL[8 * 384];
    __shared__ float WL[360];
    __shared__ float redS[4][8], redC[4][8];
    __shared__ float SevL[8], CevL[8];
    __shared__ float cpart[256];
    __shared__ float ctxL[32];
    int b = (int)blockIdx.x, tid = (int)threadIdx.x;
    int lane = tid & 63, w = tid >> 6;

    mL[tid] = mAll[b * 256 + tid];
    __syncthreads();

    float eS[8] = {0.f, 0.f, 0.f, 0.f, 0.f, 0.f, 0.f, 0.f};
    float eC[8] = {0.f, 0.f, 0.f, 0.f, 0.f, 0.f, 0.f, 0.f};
    for (int j = tid; j < NG; j += 256) {
        const float* fb = featB + ((size_t)b * NG + j) * 32;
        float v[8] = {0.f, 0.f, 0.f, 0.f, 0.f, 0.f, 0.f, 0.f};
        #pragma unroll
        for (int dc = 0; dc < 32; dc += 4) {
            float4 f = *(const float4*)(fb + dc);
            #pragma unroll
            for (int h = 0; h < 8; ++h) {
                v[h] = fmaf(f.x, mL[h * 32 + dc], v[h]);
                v[h] = fmaf(f.y, mL[h * 32 + dc + 1], v[h]);
                v[h] = fmaf(f.z, mL[h * 32 + dc + 2], v[h]);
                v[h] = fmaf(f.w, mL[h * 32 + dc + 3], v[h]);
            }
        }
        #pragma unroll
        for (int h = 0; h < 8; ++h) {
            float e = expf(v[h] * INV_SQRT_HD);
            float c = cSb[(size_t)b * 2880 + h * NG + j];
            eL[h * 384 + j] = e;
            cL[h * 384 + j] = c;
            eS[h] += e;
            eC[h] += c * e;
        }
    }
    #pragma unroll
    for (int h = 0; h < 8; ++h) {
        #pragma unroll
        for (int off = 32; off > 0; off >>= 1) {
            eS[h] += __shfl_xor(eS[h], off);
            eC[h] += __shfl_xor(eC[h], off);
        }
    }
    if (lane == 0) {
        #pragma unroll
        for (int h = 0; h < 8; ++h) { redS[w][h] = eS[h]; redC[w][h] = eC[h]; }
    }
    __syncthreads();
    if (tid < 8) {
        float s = 0.f, c = 0.f;
        #pragma unroll
        for (int ww = 0; ww < 4; ++ww) { s += redS[ww][tid]; c += redC[ww][tid]; }
        SevL[tid] = s; CevL[tid] = c;
    }
    __syncthreads();
    float invS[8], cevM[8];
    #pragma unroll
    for (int h = 0; h < 8; ++h) {
        float iv = 1.f / SevL[h];
        invS[h] = iv;
        cevM[h] = CevL[h] * iv;
    }
    for (int j = tid; j < NG; j += 256) {
        float acc = 0.f;
        #pragma unroll
        for (int h = 0; h < 8; ++h) {
            float e = eL[h * 384 + j];
            float c = cL[h * 384 + j];
            acc += e * invS[h] * (1.f + (c - cevM[h]) * (1.f / 360.f));
        }
        float W = acc * 0.125f;
        WL[j] = W;
        out[OFF_SCORES + (size_t)b * (NT * NG) + t * NG + j] = W;
    }
    __syncthreads();
    {
        int d = tid & 31, sl = tid >> 5;
        float a = 0.f;
        for (int i = 0; i < 45; ++i) {
            int j = sl * 45 + i;
            a += WL[j] * featB[((size_t)b * NG + j) * 32 + d];
        }
        cpart[tid] = a;
    }
    __syncthreads();
    if (tid < 32) {
        float s = 0.f;
        #pragma unroll
        for (int ss = 0; ss < 8; ++ss) s += cpart[ss * 32 + tid];
        ctxL[tid] = s;
    }
    __syncthreads();

    const float* gihxB = gihxT + (size_t)b * 2048;
    const float* ghhB  = ghhT + (size_t)b * 2048;
    float* cB = cT + (size_t)b * 512;
    float hv[2];
    float ssum = 0.f, qsum = 0.f;
    #pragma unroll
    for (int ii = 0; ii < 2; ++ii) {
        int u = tid + ii * 256;
        float g4[4];
        #pragma unroll
        for (int q = 0; q < 4; ++q) {
            int n = q * 512 + u;
            float gv = gihxB[n] + ghhB[n];
            const float* wr = Wc + (size_t)n * 32;
            #pragma unroll
            for (int d = 0; d < 32; d += 4) {
                float4 f = *(const float4*)(wr + d);
                gv = fmaf(ctxL[d], f.x, gv);
                gv = fmaf(ctxL[d + 1], f.y, gv);
                gv = fmaf(ctxL[d + 2], f.z, gv);
                gv = fmaf(ctxL[d + 3], f.w, gv);
            }
            g4[q] = gv;
        }
        float ig = sigm(g4[0]), fg = sigm(g4[1]), gg = tanhf(g4[2]), og = sigm(g4[3]);
        float cn = fg * cB[u] + ig * gg;
        cB[u] = cn;
        hv[ii] = og * tanhf(cn);
        ssum += hv[ii]; qsum += hv[ii] * hv[ii];
    }
    #pragma unroll
    for (int off = 32; off > 0; off >>= 1) {
        ssum += __shfl_xor(ssum, off);
        qsum += __shfl_xor(qsum, off);
    }
    if (lane == 0) { cpart[w] = ssum; cpart[8 + w] = qsum; }
    __syncthreads();
    float ms = cpart[0] + cpart[1] + cpart[2] + cpart[3];
    float qs = cpart[8] + cpart[9] + cpart[10] + cpart[11];
    float m = ms * (1.f / 512.f);
    float var = qs * (1.f / 512.f) - m * m;
    float rstd = 1.f / sqrtf(var + 1e-5f);
    float mneg = -m * rstd;
    unsigned short* srow = sbf + ((size_t)t * 64 + b) * 512;
    #pragma unroll
    for (int ii = 0; ii < 2; ++ii) {
        int u = tid + ii * 256;
        float aval = fmaf(fmaf(hv[ii], rstd, mneg), ln_g[u], ln_b[u]);
        abf[(size_t)b * 512 + u] = f2bf(aval);
        srow[u] = f2bf(leaky(aval));
    }
}

// ---------- Post-loop head ----------

__global__ __launch_bounds__(256) void kHeadMF(
        const unsigned short* __restrict__ W1x, const unsigned short* __restrict__ sbf,
        const float* __restrict__ b1, unsigned short* __restrict__ h1bf) {
    int wid = __builtin_amdgcn_readfirstlane((int)blockIdx.x * 4 + ((int)threadIdx.x >> 6));
    int lane = (int)threadIdx.x & 63;
    int mt = wid / 60, nt = wid % 60;
    int m0 = mt * 16, col = lane & 15, q = lane >> 4;
    const unsigned short* aB = W1x + (size_t)(m0 + col) * NU + q * 8;
    const unsigned short* bB = sbf + (size_t)(nt * 16 + col) * NU + q * 8;
    f32x4 acc = {0.f, 0.f, 0.f, 0.f};
    #pragma unroll
    for (int kk = 0; kk < 16; ++kk) {
        bf16x8 af = *(const bf16x8*)(aB + kk * 32);
        bf16x8 bf = *(const bf16x8*)(bB + kk * 32);
        acc = __builtin_amdgcn_mfma_f32_16x16x32_bf16(af, bf, acc, 0, 0, 0);
    }
    int gcol = nt * 16 + col;
    u16x4 pk;
    #pragma unroll
    for (int r = 0; r < 4; ++r) {
        float v = leaky(acc[r] + b1[m0 + q * 4 + r]);
        pk[r] = f2bf(v);
    }
    *(u16x4*)(h1bf + (size_t)gcol * 256 + m0 + q * 4) = pk;
}

// MFMA logits: wave = (t, mt); loops 4 ntiles reusing A fragments. 1174 blocks.
__global__ __launch_bounds__(256) void kLogitsMF(const unsigned short* __restrict__ W2bf,
                                                 const unsigned short* __restrict__ h1bfT,
                                                 const float* __restrict__ b2,
                                                 float* __restrict__ lgAll, float* __restrict__ zPm) {
    int wid = __builtin_amdgcn_readfirstlane((int)blockIdx.x * 4 + ((int)threadIdx.x >> 6));
    if (wid >= NT * 313) return;
    int lane = (int)threadIdx.x & 63;
    int t = wid / 313;
    int mt = wid - t * 313;
    int m0 = mt * 16;
    int q = lane >> 4, col = lane & 15;
    const unsigned short* aBase = W2bf + (size_t)(m0 + col) * 256 + q * 8;
    bf16x8 af[8];
    #pragma unroll
    for (int kk = 0; kk < 8; ++kk) af[kk] = *(const bf16x8*)(aBase + kk * 32);

    float b2r[4];
    #pragma unroll
    for (int r = 0; r < 4; ++r) {
        int row = m0 + q * 4 + r;
        b2r[r] = (row < NVOC) ? b2[row] : 0.f;
    }

    #pragma unroll
    for (int nt = 0; nt < 4; ++nt) {
        const unsigned short* bBase = h1bfT + ((size_t)t * 64 + nt * 16 + col) * 256 + q * 8;
        f32x4 acc = {0.f, 0.f, 0.f, 0.f};
        #pragma unroll
        for (int kk = 0; kk < 8; ++kk) {
            bf16x8 bf = *(const bf16x8*)(bBase + kk * 32);
            acc = __builtin_amdgcn_mfma_f32_16x16x32_bf16(af[kk], bf, acc, 0, 0, 0);
        }
        float eS = 0.f;
        #pragma unroll
        for (int r = 0; r < 4; ++r) {
            int row = m0 + q * 4 + r;
            if (row < NVOC) {
                float e = expf(acc[r] + b2r[r]);
                lgAll[((size_t)t * NVOC + row) * 64 + nt * 16 + col] = e;
                eS += e;
            }
        }
        eS += __shfl_xor(eS, 16);
        eS += __shfl_xor(eS, 32);
        if (lane < 16)
            zPm[((size_t)t * 313 + mt) * 64 + nt * 16 + col] = eS;
    }
}

// kOut with inline Z reduction (absorbs kZinv; same reduction grouping -> bitwise-same z)
__global__ __launch_bounds__(256) void kOut(const float* __restrict__ lgAll,
                                            const float* __restrict__ zPm, float* __restrict__ out) {
    __shared__ float tile[64 * 65];
    __shared__ float zred[256];
    int bid = (int)blockIdx.x;
    int t = bid / 79, nt = bid % 79;
    int n0 = nt * 64;
    int tid = (int)threadIdx.x, lane = tid & 63, w = tid >> 6;
    // Z for this t (per-lane = per-b), same partial grouping as the old kZinv
    float p = 0.f;
    for (int i = w; i < 313; i += 4) p += zPm[((size_t)t * 313 + i) * 64 + lane];
    zred[tid] = p;
    __syncthreads();
    float z = zred[lane] + zred[64 + lane] + zred[128 + lane] + zred[192 + lane];
    float invZ = 1.f / z;
    const float* lg = lgAll + (size_t)t * (NVOC * 64);
    for (int i = 0; i < 16; ++i) {
        int r = w * 16 + i, n = n0 + r;
        if (n < NVOC) tile[r * 65 + lane] = lg[n * 64 + lane] * invZ;
    }
    __syncthreads();
    for (int i = 0; i < 16; ++i) {
        int b = w * 16 + i;
        int n = n0 + lane;
        if (n < NVOC) out[(size_t)b * (NT * NVOC) + t * NVOC + n] = tile[lane * 65 + b];
    }
}

// ---------- Launch ----------
extern "C" void kernel_launch(void* const* d_in, const int* in_sizes, int n_in,
                              void* d_out, int out_size, void* d_ws, size_t ws_size,
                              hipStream_t stream) {
    const float* features = (const float*)d_in[0];
    const int*   text     = (const int*)d_in[1];
    const float* a0       = (const float*)d_in[2];
    const float* c0       = (const float*)d_in[3];
    const float* enc_W    = (const float*)d_in[4];
    const float* enc_b    = (const float*)d_in[5];
    const float* enc_g    = (const float*)d_in[6];
    const float* enc_beta = (const float*)d_in[7];
    const float* emb      = (const float*)d_in[8];
    const float* in_w     = (const float*)d_in[9];
    const float* in_b     = (const float*)d_in[10];
    const float* Wih      = (const float*)d_in[11];
    const float* Whh      = (const float*)d_in[12];
    const float* bih      = (const float*)d_in[13];
    const float* bhh      = (const float*)d_in[14];
    const float* ln_g     = (const float*)d_in[15];
    const float* ln_b     = (const float*)d_in[16];
    const float* W1       = (const float*)d_in[17];
    const float* b1       = (const float*)d_in[18];
    const float* W2       = (const float*)d_in[19];
    const float* b2       = (const float*)d_in[20];
    float* out = (float*)d_out;

    float* ws = (float*)d_ws;
    size_t off = 0;
    auto alloc = [&](size_t n) { float* p = ws + off; off += (n + 63) & ~(size_t)63; return p; };
    float* lgAll   = alloc((size_t)NT * NVOC * 64);   // aliased as fX pre-loop
    float* fX      = lgAll;
    float* featB   = alloc((size_t)64 * NG * ND);
    float* gihxAll = alloc((size_t)NT * 64 * 2048);
    float* mAll    = alloc((size_t)64 * 256);
    float* cSb     = alloc((size_t)64 * NH * NG);
    float* cT_     = alloc((size_t)64 * NU);
    float* ghhT    = alloc((size_t)64 * 2048);
    float* Wc      = alloc((size_t)2048 * 32);
    float* bm      = alloc((size_t)256);
    float* Wmf     = alloc((size_t)256 * 32);
    float* zPm     = alloc((size_t)NT * 313 * 64);
    unsigned short* WA2  = (unsigned short*)alloc((size_t)2304 * 256);  // [2304][512] bf16
    unsigned short* W1x  = (unsigned short*)alloc((size_t)256 * 256);
    unsigned short* abf  = (unsigned short*)alloc((size_t)64 * 256);
    unsigned short* sbf  = (unsigned short*)alloc((size_t)960 * 256);
    unsigned short* Wihx = (unsigned short*)alloc((size_t)2048 * 256);
    unsigned short* xbf  = (unsigned short*)alloc((size_t)960 * 256);
    unsigned short* W2bf = (unsigned short*)alloc((size_t)5008 * 128);
    unsigned short* h1bf = (unsigned short*)alloc((size_t)NT * 64 * 128);

    // fused pre-passes
    kPre1<<<14930, 256, 0, stream>>>(features, in_w, in_b, a0, c0, text, emb,
                                     Whh, W1, Wih, W2,
                                     fX, WA2, bm, Wmf, abf, cT_, xbf, W1x,
                                     Wihx, W2bf, Wc);
    kEncGihx<<<2280, 256, 0, stream>>>(fX, enc_W, enc_b, enc_g, enc_beta, featB,
                                       Wihx, xbf, bih, bhh, gihxAll);
    kCS2<<<64, 256, 0, stream>>>(featB, Wmf, cSb);

    for (int t = 0; t < NT; ++t) {
        kAMF2<<<144, 256, 0, stream>>>(WA2, bm, abf, mAll, ghhT);
        kStep<<<64, 256, 0, stream>>>(mAll, featB, cSb,
                                      gihxAll + (size_t)t * 64 * 2048, ghhT, Wc,
                                      ln_g, ln_b, cT_, abf, sbf, out, t);
    }

    kHeadMF<<<240, 256, 0, stream>>>(W1x, sbf, b1, h1bf);
    kLogitsMF<<<1174, 256, 0, stream>>>(W2bf, h1bf, b2, lgAll, zPm);
    kOut<<<NT * 79, 256, 0, stream>>>(lgAll, zPm, out);
}

// Round 11
// 580.894 us; speedup vs baseline: 1.0315x; 1.0140x over previous
//
#include <hip/hip_runtime.h>
#include <math.h>

#define NG 360
#define NV 100
#define ND 32
#define NU 512
#define NT 15
#define NVOC 5000
#define NH 8
#define NE 544
#define NHD 68
#define OFF_SCORES 4800000
#define INV_SQRT_HD 0.12126781f
#define CS_SCALE 43.65636f

typedef short bf16x8 __attribute__((ext_vector_type(8)));
typedef float f32x4 __attribute__((ext_vector_type(4)));
typedef unsigned short u16x4 __attribute__((ext_vector_type(4)));

__device__ __forceinline__ float leaky(float x) { return x >= 0.f ? x : 0.2f * x; }
__device__ __forceinline__ float sigm(float x) { return 1.f / (1.f + expf(-x)); }
__device__ __forceinline__ unsigned short f2bf(float x) {
    unsigned b = __float_as_uint(x);
    return (unsigned short)((b + 0x7FFFu + ((b >> 16) & 1u)) >> 16);
}

// ---------- Fused pre-pass 1: all input-only work ----------
// blocks [0,256): kWm (Wm fold -> WA2 rows 0..255, bm, Wmf)
// [256,384): kInit (abf, cT)
// [384,399): kEmbed
// [399,14367): kPrep (weight converts)
__global__ __launch_bounds__(256) void kPre1(
        const float* __restrict__ in_w,
        const float* __restrict__ in_b, const float* __restrict__ a0,
        const float* __restrict__ c0, const int* __restrict__ text,
        const float* __restrict__ emb, const float* __restrict__ Whh,
        const float* __restrict__ W1, const float* __restrict__ Wih,
        const float* __restrict__ W2,
        unsigned short* __restrict__ WA2,
        float* __restrict__ bm, float* __restrict__ Wmf,
        unsigned short* __restrict__ abf, float* __restrict__ cT,
        unsigned short* __restrict__ xbf, unsigned short* __restrict__ W1x,
        unsigned short* __restrict__ Wihx, unsigned short* __restrict__ W2bf,
        float* __restrict__ Wc) {
    __shared__ float wk[68];
    int bid = (int)blockIdx.x, tid = (int)threadIdx.x;

    if (bid < 256) {
        // kWm: r = bid
        int r = bid;
        int h = r >> 5, c = r & 31;
        if (tid < 68) wk[tid] = in_w[(size_t)(NE + h * NHD + tid) * NE + c];
        __syncthreads();
        float a0_ = 0.f, a1 = 0.f;
        for (int d = 0; d < NHD; ++d) {
            const float* wq = in_w + (size_t)(h * NHD + d) * NE + 32;
            float wkd = wk[d];
            a0_ = fmaf(wkd, wq[tid], a0_);
            a1 = fmaf(wkd, wq[tid + 256], a1);
        }
        WA2[(size_t)r * 512 + tid] = f2bf(a0_);
        WA2[(size_t)r * 512 + tid + 256] = f2bf(a1);
        // Wmf[r][d] = sum_e wk[e] * Wq[e][d] (feature cols 0..31), fp32
        if (tid < 32) {
            float a = 0.f;
            for (int e = 0; e < NHD; ++e)
                a = fmaf(wk[e], in_w[(size_t)(h * NHD + e) * NE + tid], a);
            Wmf[r * 32 + tid] = a;
        }
        __syncthreads();
        if (tid < 68) wk[tid] = wk[tid] * in_b[h * NHD + tid];
        __syncthreads();
        if (tid == 0) {
            float s = 0.f;
            for (int d = 0; d < NHD; ++d) s += wk[d];
            bm[r] = s;
        }
        return;
    }
    if (bid < 384) {
        int idx = (bid - 256) * 256 + tid;
        abf[idx] = f2bf(a0[idx]);
        cT[idx] = c0[idx];
        return;
    }
    if (bid < 399) {
        int t = bid - 384;
        int b = tid >> 2, seg = (tid & 3) * 128;
        int row = text[b * NT + t];
        const float* er = emb + (size_t)row * NU;
        unsigned short* dst = xbf + ((size_t)t * 64 + b) * 512;
        for (int i = 0; i < 128; ++i) dst[seg + i] = f2bf(er[seg + i]);
        return;
    }
    {
        int idx = (bid - 399) * 256 + tid;
        if (idx < 1048576) {                       // Whh [2048][512]
            WA2[256 * 512 + idx] = f2bf(Whh[idx]);
        } else if ((idx -= 1048576) < 131072) {    // W1 [256][512]
            W1x[idx] = f2bf(W1[idx]);
        } else if ((idx -= 131072) < 1048576) {    // Wih cols 32.. -> Wihx
            int r = idx >> 9, k = idx & 511;
            Wihx[idx] = f2bf(Wih[(size_t)r * NE + 32 + k]);
        } else if ((idx -= 1048576) < 1282048) {   // W2 + 8 pad rows
            W2bf[idx] = (idx < 1280000) ? f2bf(W2[idx]) : (unsigned short)0;
        } else {                                   // Wc [2048][32]
            idx -= 1282048;
            int r = idx >> 5, d = idx & 31;
            Wc[idx] = Wih[(size_t)r * NE + d];
        }
        return;
    }
}

// ---------- Fused pre-pass 2: encoder (blocks 0..359, features + enc_W staged in LDS)
//            + gihx MFMA (blocks 360..2279) — overlapped in one launch ----------
__global__ __launch_bounds__(256) void kEncGihx(
        const float* __restrict__ features, const float* __restrict__ enc_W,
        const float* __restrict__ enc_b, const float* __restrict__ enc_g,
        const float* __restrict__ enc_beta, float* __restrict__ featB,
        const unsigned short* __restrict__ Wihx, const unsigned short* __restrict__ xbf,
        const float* __restrict__ bih, const float* __restrict__ bhh,
        float* __restrict__ gihxAll) {
    __shared__ float fxs[100 * 65];
    __shared__ float wbs[3200];
    __shared__ float ps[256], pq[256];
    int bid = (int)blockIdx.x, tid = (int)threadIdx.x;
    if (bid < NG) {
        int g = bid;
        // load features[b][g*100+v] -> fxs[v*65+b] directly (v-contiguous reads)
        {
            const float* fbase = features + g * 100;
            int v = tid & 127;
            int bhalf = tid >> 7;
            if (v < 100) {
                #pragma unroll
                for (int i = 0; i < 32; ++i) {
                    int b = (i << 1) + bhalf;
                    fxs[v * 65 + b] = fbase[(size_t)b * (NG * NV) + v];
                }
            }
        }
        for (int k = tid; k < 3200; k += 256) wbs[k] = enc_W[(size_t)g * 3200 + k];
        __syncthreads();
        int lane = tid & 63, w = tid >> 6, d0 = w * 8;
        float acc[8];
        #pragma unroll
        for (int j = 0; j < 8; ++j) acc[j] = enc_b[g * 32 + d0 + j];
        const float* wb = wbs + d0 * 100;
        #pragma unroll 4
        for (int v = 0; v < 100; ++v) {
            float fv = fxs[v * 65 + lane];
            #pragma unroll
            for (int j = 0; j < 8; ++j) acc[j] += fv * wb[j * 100 + v];
        }
        float sm = 0.f, sq = 0.f;
        #pragma unroll
        for (int j = 0; j < 8; ++j) { sm += acc[j]; sq += acc[j] * acc[j]; }
        ps[tid] = sm; pq[tid] = sq;
        __syncthreads();
        float m = (ps[lane] + ps[64 + lane] + ps[128 + lane] + ps[192 + lane]) * (1.f / 32.f);
        float q = (pq[lane] + pq[64 + lane] + pq[128 + lane] + pq[192 + lane]);
        float var = q * (1.f / 32.f) - m * m;
        float rstd = 1.f / sqrtf(var + 1e-5f);
        #pragma unroll
        for (int j = 0; j < 8; ++j) {
            int d = d0 + j;
            float x = (acc[j] - m) * rstd * enc_g[d] + enc_beta[d];
            featB[((size_t)lane * NG + g) * 32 + d] = leaky(x);
        }
        return;
    }
    // gihx MFMA
    int wid = __builtin_amdgcn_readfirstlane((bid - NG) * 4 + (tid >> 6));
    int lane = tid & 63;
    int mt = wid / 60, nt = wid % 60;
    int m0 = mt * 16, col = lane & 15, q = lane >> 4;
    const unsigned short* aB = Wihx + (size_t)(m0 + col) * 512 + q * 8;
    const unsigned short* bB = xbf + (size_t)(nt * 16 + col) * 512 + q * 8;
    f32x4 acc = {0.f, 0.f, 0.f, 0.f};
    #pragma unroll
    for (int kk = 0; kk < 16; ++kk) {
        bf16x8 af = *(const bf16x8*)(aB + kk * 32);
        bf16x8 bf = *(const bf16x8*)(bB + kk * 32);
        acc = __builtin_amdgcn_mfma_f32_16x16x32_bf16(af, bf, acc, 0, 0, 0);
    }
    int gcol = nt * 16 + col, t = gcol >> 6, b = gcol & 63;
    int n0 = m0 + q * 4;
    float4 o;
    o.x = acc[0] + bih[n0] + bhh[n0];
    o.y = acc[1] + bih[n0 + 1] + bhh[n0 + 1];
    o.z = acc[2] + bih[n0 + 2] + bhh[n0 + 2];
    o.w = acc[3] + bih[n0 + 3] + bhh[n0 + 3];
    *(float4*)(gihxAll + ((size_t)(t * 64 + b)) * 2048 + n0) = o;
}

// ---------- Fused pre-pass 3: fmean_b + mq_b + cSb, 64 blocks (one per b) ----------
__global__ __launch_bounds__(256) void kCS2(const float* __restrict__ featB,
                                            const float* __restrict__ Wmf,
                                            float* __restrict__ cSb) {
    __shared__ float red[256];
    __shared__ float fmeanL[32];
    __shared__ float mqL[256];
    int b = (int)blockIdx.x, tid = (int)threadIdx.x;
    int s = tid >> 5, d = tid & 31;
    float acc = 0.f;
    for (int g = s; g < NG; g += 8) acc += featB[((size_t)b * NG + g) * 32 + d];
    red[tid] = acc;
    __syncthreads();
    if (tid < 32) {
        float f = 0.f;
        #pragma unroll
        for (int ss = 0; ss < 8; ++ss) f += red[ss * 32 + tid];
        fmeanL[tid] = f * (1.f / 360.f);
    }
    __syncthreads();
    {
        const float* wr = Wmf + tid * 32;
        float a = 0.f;
        #pragma unroll
        for (int dd = 0; dd < 32; dd += 4) {
            float4 f4 = *(const float4*)(wr + dd);
            a = fmaf(f4.x, fmeanL[dd], a);
            a = fmaf(f4.y, fmeanL[dd + 1], a);
            a = fmaf(f4.z, fmeanL[dd + 2], a);
            a = fmaf(f4.w, fmeanL[dd + 3], a);
        }
        mqL[tid] = a;
    }
    __syncthreads();
    for (int j = tid; j < NG; j += 256) {
        const float* fb = featB + ((size_t)b * NG + j) * 32;
        float v[8] = {0.f, 0.f, 0.f, 0.f, 0.f, 0.f, 0.f, 0.f};
        #pragma unroll
        for (int dc = 0; dc < 32; dc += 4) {
            float4 f = *(const float4*)(fb + dc);
            #pragma unroll
            for (int h = 0; h < 8; ++h) {
                v[h] = fmaf(f.x, mqL[h * 32 + dc], v[h]);
                v[h] = fmaf(f.y, mqL[h * 32 + dc + 1], v[h]);
                v[h] = fmaf(f.z, mqL[h * 32 + dc + 2], v[h]);
                v[h] = fmaf(f.w, mqL[h * 32 + dc + 3], v[h]);
            }
        }
        #pragma unroll
        for (int h = 0; h < 8; ++h)
            cSb[(size_t)b * 2880 + h * NG + j] = v[h] * CS_SCALE;
    }
}

// ---------- Per-step ----------

// MFMA: [m(256); ghh(2048)] = WA2[2304][512] · abf[64][512]^T. 144 blocks.
__global__ __launch_bounds__(256) void kAMF2(
        const unsigned short* __restrict__ WA2, const float* __restrict__ bm,
        const unsigned short* __restrict__ abf,
        float* __restrict__ mAll, float* __restrict__ ghhT) {
    int wid = __builtin_amdgcn_readfirstlane((int)blockIdx.x * 4 + ((int)threadIdx.x >> 6));
    int lane = (int)threadIdx.x & 63;
    int mt = wid >> 2, bt = wid & 3;
    int m0 = mt * 16, col = lane & 15, q = lane >> 4;
    const unsigned short* aB = WA2 + (size_t)(m0 + col) * NU + q * 8;
    const unsigned short* bB = abf + (size_t)(bt * 16 + col) * NU + q * 8;
    f32x4 acc = {0.f, 0.f, 0.f, 0.f};
    #pragma unroll
    for (int kk = 0; kk < 16; ++kk) {
        bf16x8 af = *(const bf16x8*)(aB + kk * 32);
        bf16x8 bf = *(const bf16x8*)(bB + kk * 32);
        acc = __builtin_amdgcn_mfma_f32_16x16x32_bf16(af, bf, acc, 0, 0, 0);
    }
    int b = bt * 16 + col;
    if (m0 < 256) {
        #pragma unroll
        for (int r = 0; r < 4; ++r) {
            int row = m0 + q * 4 + r;
            mAll[b * 256 + row] = acc[r] + bm[row];
        }
    } else {
        int n0 = m0 - 256 + q * 4;
        float4 o; o.x = acc[0]; o.y = acc[1]; o.z = acc[2]; o.w = acc[3];
        *(float4*)(ghhT + (size_t)b * 2048 + n0) = o;
    }
}

// Fused step: attention + LSTM + LN + emit abf/sbf. 64 blocks, one per b.
__global__ __launch_bounds__(256) void kStep(
        const float* __restrict__ mAll,
        const float* __restrict__ featB, const float* __restrict__ cSb,
        const float* __restrict__ gihxT, const float* __restrict__ ghhT,
        const float* __restrict__ Wc,
        const float* __restrict__ ln_g, const float* __restrict__ ln_b,
        float* __restrict__ cT,
        unsigned short* __restrict__ abf, unsigned short* __restrict__ sbf,
        float* __restrict__ out, int t) {
    __shared__ float mL[256];
    __shared__ float eL[8 * 384];
    __shared__ float cL[8 * 384];
    __shared__ float WL[360];
    __shared__ float redS[4][8], redC[4][8];
    __shared__ float SevL[8], CevL[8];
    __shared__ float cpart[256];
    __shared__ float ctxL[32];
    int b = (int)blockIdx.x, tid = (int)threadIdx.x;
    int lane = tid & 63, w = tid >> 6;

    mL[tid] = mAll[b * 256 + tid];
    __syncthreads();

    float eS[8] = {0.f, 0.f, 0.f, 0.f, 0.f, 0.f, 0.f, 0.f};
    float eC[8] = {0.f, 0.f, 0.f, 0.f, 0.f, 0.f, 0.f, 0.f};
    for (int j = tid; j < NG; j += 256) {
        const float* fb = featB + ((size_t)b * NG + j) * 32;
        float v[8] = {0.f, 0.f, 0.f, 0.f, 0.f, 0.f, 0.f, 0.f};
        #pragma unroll
        for (int dc = 0; dc < 32; dc += 4) {
            float4 f = *(const float4*)(fb + dc);
            #pragma unroll
            for (int h = 0; h < 8; ++h) {
                v[h] = fmaf(f.x, mL[h * 32 + dc], v[h]);
                v[h] = fmaf(f.y, mL[h * 32 + dc + 1], v[h]);
                v[h] = fmaf(f.z, mL[h * 32 + dc + 2], v[h]);
                v[h] = fmaf(f.w, mL[h * 32 + dc + 3], v[h]);
            }
        }
        #pragma unroll
        for (int h = 0; h < 8; ++h) {
            float e = expf(v[h] * INV_SQRT_HD);
            float c = cSb[(size_t)b * 2880 + h * NG + j];
            eL[h * 384 + j] = e;
            cL[h * 384 + j] = c;
            eS[h] += e;
            eC[h] += c * e;
        }
    }
    #pragma unroll
    for (int h = 0; h < 8; ++h) {
        #pragma unroll
        for (int off = 32; off > 0; off >>= 1) {
            eS[h] += __shfl_xor(eS[h], off);
            eC[h] += __shfl_xor(eC[h], off);
        }
    }
    if (lane == 0) {
        #pragma unroll
        for (int h = 0; h < 8; ++h) { redS[w][h] = eS[h]; redC[w][h] = eC[h]; }
    }
    __syncthreads();
    if (tid < 8) {
        float s = 0.f, c = 0.f;
        #pragma unroll
        for (int ww = 0; ww < 4; ++ww) { s += redS[ww][tid]; c += redC[ww][tid]; }
        SevL[tid] = s; CevL[tid] = c;
    }
    __syncthreads();
    float invS[8], cevM[8];
    #pragma unroll
    for (int h = 0; h < 8; ++h) {
        float iv = 1.f / SevL[h];
        invS[h] = iv;
        cevM[h] = CevL[h] * iv;
    }
    for (int j = tid; j < NG; j += 256) {
        float acc = 0.f;
        #pragma unroll
        for (int h = 0; h < 8; ++h) {
            float e = eL[h * 384 + j];
            float c = cL[h * 384 + j];
            acc += e * invS[h] * (1.f + (c - cevM[h]) * (1.f / 360.f));
        }
        float W = acc * 0.125f;
        WL[j] = W;
        out[OFF_SCORES + (size_t)b * (NT * NG) + t * NG + j] = W;
    }
    __syncthreads();
    {
        int d = tid & 31, sl = tid >> 5;
        float a = 0.f;
        for (int i = 0; i < 45; ++i) {
            int j = sl * 45 + i;
            a += WL[j] * featB[((size_t)b * NG + j) * 32 + d];
        }
        cpart[tid] = a;
    }
    __syncthreads();
    if (tid < 32) {
        float s = 0.f;
        #pragma unroll
        for (int ss = 0; ss < 8; ++ss) s += cpart[ss * 32 + tid];
        ctxL[tid] = s;
    }
    __syncthreads();

    const float* gihxB = gihxT + (size_t)b * 2048;
    const float* ghhB  = ghhT + (size_t)b * 2048;
    float* cB = cT + (size_t)b * 512;
    float hv[2];
    float ssum = 0.f, qsum = 0.f;
    #pragma unroll
    for (int ii = 0; ii < 2; ++ii) {
        int u = tid + ii * 256;
        float g4[4];
        #pragma unroll
        for (int q = 0; q < 4; ++q) {
            int n = q * 512 + u;
            float gv = gihxB[n] + ghhB[n];
            const float* wr = Wc + (size_t)n * 32;
            #pragma unroll
            for (int d = 0; d < 32; d += 4) {
                float4 f = *(const float4*)(wr + d);
                gv = fmaf(ctxL[d], f.x, gv);
                gv = fmaf(ctxL[d + 1], f.y, gv);
                gv = fmaf(ctxL[d + 2], f.z, gv);
                gv = fmaf(ctxL[d + 3], f.w, gv);
            }
            g4[q] = gv;
        }
        float ig = sigm(g4[0]), fg = sigm(g4[1]), gg = tanhf(g4[2]), og = sigm(g4[3]);
        float cn = fg * cB[u] + ig * gg;
        cB[u] = cn;
        hv[ii] = og * tanhf(cn);
        ssum += hv[ii]; qsum += hv[ii] * hv[ii];
    }
    #pragma unroll
    for (int off = 32; off > 0; off >>= 1) {
        ssum += __shfl_xor(ssum, off);
        qsum += __shfl_xor(qsum, off);
    }
    if (lane == 0) { cpart[w] = ssum; cpart[8 + w] = qsum; }
    __syncthreads();
    float ms = cpart[0] + cpart[1] + cpart[2] + cpart[3];
    float qs = cpart[8] + cpart[9] + cpart[10] + cpart[11];
    float m = ms * (1.f / 512.f);
    float var = qs * (1.f / 512.f) - m * m;
    float rstd = 1.f / sqrtf(var + 1e-5f);
    float mneg = -m * rstd;
    unsigned short* srow = sbf + ((size_t)t * 64 + b) * 512;
    #pragma unroll
    for (int ii = 0; ii < 2; ++ii) {
        int u = tid + ii * 256;
        float aval = fmaf(fmaf(hv[ii], rstd, mneg), ln_g[u], ln_b[u]);
        abf[(size_t)b * 512 + u] = f2bf(aval);
        srow[u] = f2bf(leaky(aval));
    }
}

// ---------- Post-loop head ----------

__global__ __launch_bounds__(256) void kHeadMF(
        const unsigned short* __restrict__ W1x, const unsigned short* __restrict__ sbf,
        const float* __restrict__ b1, unsigned short* __restrict__ h1bf) {
    int wid = __builtin_amdgcn_readfirstlane((int)blockIdx.x * 4 + ((int)threadIdx.x >> 6));
    int lane = (int)threadIdx.x & 63;
    int mt = wid / 60, nt = wid % 60;
    int m0 = mt * 16, col = lane & 15, q = lane >> 4;
    const unsigned short* aB = W1x + (size_t)(m0 + col) * NU + q * 8;
    const unsigned short* bB = sbf + (size_t)(nt * 16 + col) * NU + q * 8;
    f32x4 acc = {0.f, 0.f, 0.f, 0.f};
    #pragma unroll
    for (int kk = 0; kk < 16; ++kk) {
        bf16x8 af = *(const bf16x8*)(aB + kk * 32);
        bf16x8 bf = *(const bf16x8*)(bB + kk * 32);
        acc = __builtin_amdgcn_mfma_f32_16x16x32_bf16(af, bf, acc, 0, 0, 0);
    }
    int gcol = nt * 16 + col;
    u16x4 pk;
    #pragma unroll
    for (int r = 0; r < 4; ++r) {
        float v = leaky(acc[r] + b1[m0 + q * 4 + r]);
        pk[r] = f2bf(v);
    }
    *(u16x4*)(h1bf + (size_t)gcol * 256 + m0 + q * 4) = pk;
}

// MFMA logits: wave = (t, mt); loops 4 ntiles reusing A fragments. 1174 blocks.
__global__ __launch_bounds__(256) void kLogitsMF(const unsigned short* __restrict__ W2bf,
                                                 const unsigned short* __restrict__ h1bfT,
                                                 const float* __restrict__ b2,
                                                 float* __restrict__ lgAll, float* __restrict__ zPm) {
    int wid = __builtin_amdgcn_readfirstlane((int)blockIdx.x * 4 + ((int)threadIdx.x >> 6));
    if (wid >= NT * 313) return;
    int lane = (int)threadIdx.x & 63;
    int t = wid / 313;
    int mt = wid - t * 313;
    int m0 = mt * 16;
    int q = lane >> 4, col = lane & 15;
    const unsigned short* aBase = W2bf + (size_t)(m0 + col) * 256 + q * 8;
    bf16x8 af[8];
    #pragma unroll
    for (int kk = 0; kk < 8; ++kk) af[kk] = *(const bf16x8*)(aBase + kk * 32);

    float b2r[4];
    #pragma unroll
    for (int r = 0; r < 4; ++r) {
        int row = m0 + q * 4 + r;
        b2r[r] = (row < NVOC) ? b2[row] : 0.f;
    }

    #pragma unroll
    for (int nt = 0; nt < 4; ++nt) {
        const unsigned short* bBase = h1bfT + ((size_t)t * 64 + nt * 16 + col) * 256 + q * 8;
        f32x4 acc = {0.f, 0.f, 0.f, 0.f};
        #pragma unroll
        for (int kk = 0; kk < 8; ++kk) {
            bf16x8 bf = *(const bf16x8*)(bBase + kk * 32);
            acc = __builtin_amdgcn_mfma_f32_16x16x32_bf16(af[kk], bf, acc, 0, 0, 0);
        }
        float eS = 0.f;
        #pragma unroll
        for (int r = 0; r < 4; ++r) {
            int row = m0 + q * 4 + r;
            if (row < NVOC) {
                float e = expf(acc[r] + b2r[r]);
                lgAll[((size_t)t * NVOC + row) * 64 + nt * 16 + col] = e;
                eS += e;
            }
        }
        eS += __shfl_xor(eS, 16);
        eS += __shfl_xor(eS, 32);
        if (lane < 16)
            zPm[((size_t)t * 313 + mt) * 64 + nt * 16 + col] = eS;
    }
}

// kOut with inline Z reduction (absorbs kZinv; same reduction grouping -> bitwise-same z)
__global__ __launch_bounds__(256) void kOut(const float* __restrict__ lgAll,
                                            const float* __restrict__ zPm, float* __restrict__ out) {
    __shared__ float tile[64 * 65];
    __shared__ float zred[256];
    int bid = (int)blockIdx.x;
    int t = bid / 79, nt = bid % 79;
    int n0 = nt * 64;
    int tid = (int)threadIdx.x, lane = tid & 63, w = tid >> 6;
    // Z for this t (per-lane = per-b), same partial grouping as the old kZinv
    float p = 0.f;
    for (int i = w; i < 313; i += 4) p += zPm[((size_t)t * 313 + i) * 64 + lane];
    zred[tid] = p;
    __syncthreads();
    float z = zred[lane] + zred[64 + lane] + zred[128 + lane] + zred[192 + lane];
    float invZ = 1.f / z;
    const float* lg = lgAll + (size_t)t * (NVOC * 64);
    for (int i = 0; i < 16; ++i) {
        int r = w * 16 + i, n = n0 + r;
        if (n < NVOC) tile[r * 65 + lane] = lg[n * 64 + lane] * invZ;
    }
    __syncthreads();
    for (int i = 0; i < 16; ++i) {
        int b = w * 16 + i;
        int n = n0 + lane;
        if (n < NVOC) out[(size_t)b * (NT * NVOC) + t * NVOC + n] = tile[lane * 65 + b];
    }
}

// ---------- Launch ----------
extern "C" void kernel_launch(void* const* d_in, const int* in_sizes, int n_in,
                              void* d_out, int out_size, void* d_ws, size_t ws_size,
                              hipStream_t stream) {
    const float* features = (const float*)d_in[0];
    const int*   text     = (const int*)d_in[1];
    const float* a0       = (const float*)d_in[2];
    const float* c0       = (const float*)d_in[3];
    const float* enc_W    = (const float*)d_in[4];
    const float* enc_b    = (const float*)d_in[5];
    const float* enc_g    = (const float*)d_in[6];
    const float* enc_beta = (const float*)d_in[7];
    const float* emb      = (const float*)d_in[8];
    const float* in_w     = (const float*)d_in[9];
    const float* in_b     = (const float*)d_in[10];
    const float* Wih      = (const float*)d_in[11];
    const float* Whh      = (const float*)d_in[12];
    const float* bih      = (const float*)d_in[13];
    const float* bhh      = (const float*)d_in[14];
    const float* ln_g     = (const float*)d_in[15];
    const float* ln_b     = (const float*)d_in[16];
    const float* W1       = (const float*)d_in[17];
    const float* b1       = (const float*)d_in[18];
    const float* W2       = (const float*)d_in[19];
    const float* b2       = (const float*)d_in[20];
    float* out = (float*)d_out;

    float* ws = (float*)d_ws;
    size_t off = 0;
    auto alloc = [&](size_t n) { float* p = ws + off; off += (n + 63) & ~(size_t)63; return p; };
    float* lgAll   = alloc((size_t)NT * NVOC * 64);
    float* featB   = alloc((size_t)64 * NG * ND);
    float* gihxAll = alloc((size_t)NT * 64 * 2048);
    float* mAll    = alloc((size_t)64 * 256);
    float* cSb     = alloc((size_t)64 * NH * NG);
    float* cT_     = alloc((size_t)64 * NU);
    float* ghhT    = alloc((size_t)64 * 2048);
    float* Wc      = alloc((size_t)2048 * 32);
    float* bm      = alloc((size_t)256);
    float* Wmf     = alloc((size_t)256 * 32);
    float* zPm     = alloc((size_t)NT * 313 * 64);
    unsigned short* WA2  = (unsigned short*)alloc((size_t)2304 * 256);  // [2304][512] bf16
    unsigned short* W1x  = (unsigned short*)alloc((size_t)256 * 256);
    unsigned short* abf  = (unsigned short*)alloc((size_t)64 * 256);
    unsigned short* sbf  = (unsigned short*)alloc((size_t)960 * 256);
    unsigned short* Wihx = (unsigned short*)alloc((size_t)2048 * 256);
    unsigned short* xbf  = (unsigned short*)alloc((size_t)960 * 256);
    unsigned short* W2bf = (unsigned short*)alloc((size_t)5008 * 128);
    unsigned short* h1bf = (unsigned short*)alloc((size_t)NT * 64 * 128);

    // fused pre-passes
    kPre1<<<14367, 256, 0, stream>>>(in_w, in_b, a0, c0, text, emb,
                                     Whh, W1, Wih, W2,
                                     WA2, bm, Wmf, abf, cT_, xbf, W1x,
                                     Wihx, W2bf, Wc);
    kEncGihx<<<2280, 256, 0, stream>>>(features, enc_W, enc_b, enc_g, enc_beta, featB,
                                       Wihx, xbf, bih, bhh, gihxAll);
    kCS2<<<64, 256, 0, stream>>>(featB, Wmf, cSb);

    for (int t = 0; t < NT; ++t) {
        kAMF2<<<144, 256, 0, stream>>>(WA2, bm, abf, mAll, ghhT);
        kStep<<<64, 256, 0, stream>>>(mAll, featB, cSb,
                                      gihxAll + (size_t)t * 64 * 2048, ghhT, Wc,
                                      ln_g, ln_b, cT_, abf, sbf, out, t);
    }

    kHeadMF<<<240, 256, 0, stream>>>(W1x, sbf, b1, h1bf);
    kLogitsMF<<<1174, 256, 0, stream>>>(W2bf, h1bf, b2, lgAll, zPm);
    kOut<<<NT * 79, 256, 0, stream>>>(lgAll, zPm, out);
}